// Round 4
// baseline (158.300 us; speedup 1.0000x reference)
//
#include <hip/hip_runtime.h>
#include <cstdint>
#include <cstddef>

#define DZc   128
#define Lc    256
#define Hc    4
#define DCc   32
#define DHCc  128
#define NPOSc (Lc * Lc)

typedef __attribute__((ext_vector_type(8))) short bf16x8;
typedef __attribute__((ext_vector_type(4))) float f32x4;

static __device__ __forceinline__ unsigned short f2bf(float f) {
  unsigned u = __float_as_uint(f);
  u += 0x7FFFu + ((u >> 16) & 1u);     // round-to-nearest-even
  return (unsigned short)(u >> 16);
}
static __device__ __forceinline__ float bf2f(unsigned short h) {
  return __uint_as_float(((unsigned)h) << 16);
}
static __device__ __forceinline__ float sigmoidf_(float x) {
  return 1.0f / (1.0f + __expf(-x));
}

// ---------------------------------------------------------------------------
// prep+stats: blocks 0..4 transpose weights fp32 [k][j] -> bf16 [j][k]
// (q-scale folded into wq; slot 4 = w2 -> w2T[c][k]).
// Blocks 5..260: per-position LayerNorm stats (mu, rsqrt) over DZ.
// ---------------------------------------------------------------------------
__global__ __launch_bounds__(256) void prep_stats(
    const float* __restrict__ wq, const float* __restrict__ wk,
    const float* __restrict__ wv, const float* __restrict__ wg,
    const float* __restrict__ w2, const float* __restrict__ z,
    unsigned short* __restrict__ wT,
    float* __restrict__ mus, float* __restrict__ rsts)
{
  const int b = blockIdx.x;
  const int t = threadIdx.x;
  if (b < 5) {
    const float* src = (b == 0) ? wq : (b == 1) ? wk : (b == 2) ? wv : (b == 3) ? wg : w2;
    unsigned short* dst = wT + (size_t)b * (DZc * DHCc);
    const float scale = (b == 0) ? 0.17677669529663687f : 1.0f;  // sqrt(1/32)
    for (int p = 0; p < 64; ++p) {
      const int idx = p * 256 + t;             // 16384 elements
      const int kk = idx >> 7, j = idx & 127;  // src[kk][j]
      dst[j * 128 + kk] = f2bf(src[idx] * scale);
    }
  } else {
    const int pos = (b - 5) * 256 + t;
    float s = 0.f, s2 = 0.f;
    #pragma unroll 8
    for (int c = 0; c < DZc; ++c) {
      const float x = z[(size_t)c * NPOSc + pos];
      s += x; s2 += x * x;
    }
    const float mu = s * (1.0f / DZc);
    const float var = s2 * (1.0f / DZc) - mu * mu;
    mus[pos]  = mu;
    rsts[pos] = rsqrtf(var + 1e-5f);
  }
}

// ---------------------------------------------------------------------------
// K1 v2: LN-apply + 4 projections via MFMA. 128 pos/block, LDS = znl only.
//   Phase A: column-wise z reads (wave-uniform c), LN, conflict-free b128
//   swizzled znl writes. Phase B: 8 i-tiles GEMM, one weight per wave.
// ---------------------------------------------------------------------------
__global__ __launch_bounds__(256, 4) void ln_qkvg_mfma(
    const float* __restrict__ z, const float* __restrict__ lnw, const float* __restrict__ lnb,
    const unsigned short* __restrict__ wT,
    const float* __restrict__ mus, const float* __restrict__ rsts,
    const float* __restrict__ bq, const float* __restrict__ bk,
    const float* __restrict__ bv, const float* __restrict__ bg,
    unsigned short* __restrict__ q_ws, unsigned short* __restrict__ k_ws,
    unsigned short* __restrict__ v_ws, unsigned short* __restrict__ g_ws)
{
  __shared__ unsigned short znl[128 * DZc];   // 32 KB bf16 [i][c], XOR-swizzled

  const int t = threadIdx.x;
  const int pos0 = blockIdx.x * 128;
  const int w  = t >> 6;          // wave = weight index (0=q,1=k,2=v,3=g)
  const int l  = t & 63;
  const int lr = l & 15;
  const int lg = l >> 4;

  // ---- B-frags (registers), issued early ----
  const unsigned short* wTw = wT + (size_t)w * (DZc * DHCc);
  bf16x8 bfrag[8][4];
  #pragma unroll
  for (int jt = 0; jt < 8; ++jt)
    #pragma unroll
    for (int kt = 0; kt < 4; ++kt)
      bfrag[jt][kt] = *reinterpret_cast<const bf16x8*>(
          &wTw[(jt * 16 + lr) * 128 + kt * 32 + lg * 8]);

  const float* bptr = (w == 0) ? bq : (w == 1) ? bk : (w == 2) ? bv : bg;
  float bias[8];
  #pragma unroll
  for (int jt = 0; jt < 8; ++jt) {
    float bb = bptr[jt * 16 + lr];
    if (w == 0) bb *= 0.17677669529663687f;
    bias[jt] = bb;
  }

  // ---- Phase A: LN apply, pack, swizzled b128 znl writes ----
  {
    const int i = t & 127;                  // local pos (1 per thread)
    const int cbase = (t >> 7) * 64;        // wave-uniform c half
    const int gpos = pos0 + i;
    const float mu = mus[gpos], rs = rsts[gpos];
    #pragma unroll
    for (int cc = 0; cc < 64; cc += 8) {
      unsigned short pk[8];
      #pragma unroll
      for (int e = 0; e < 8; ++e) {
        const int c = cbase + cc + e;
        const float x = z[(size_t)c * NPOSc + gpos];
        pk[e] = f2bf((x - mu) * rs * lnw[c] + lnb[c]);
      }
      int byte = i * 256 + (cbase + cc) * 2;
      byte ^= ((i & 7) << 4);
      *reinterpret_cast<bf16x8*>(reinterpret_cast<char*>(znl) + byte) =
          *reinterpret_cast<const bf16x8*>(pk);
    }
  }
  __syncthreads();

  // ---- Phase B: GEMM, 8 i-tiles x 8 j-tiles x 4 k-steps ----
  unsigned short* outp = (w == 0) ? q_ws : (w == 1) ? k_ws : (w == 2) ? v_ws : g_ws;
  const char* znlb = reinterpret_cast<const char*>(znl);
  #pragma unroll 1
  for (int it = 0; it < 8; ++it) {
    bf16x8 afrag[4];
    #pragma unroll
    for (int kt = 0; kt < 4; ++kt) {
      const int i = it * 16 + lr;
      int byte = i * 256 + (kt * 64 + lg * 16);
      byte ^= ((i & 7) << 4);
      afrag[kt] = *reinterpret_cast<const bf16x8*>(znlb + byte);
    }
    f32x4 acc[8];
    #pragma unroll
    for (int jt = 0; jt < 8; ++jt) acc[jt] = (f32x4){0.f, 0.f, 0.f, 0.f};
    #pragma unroll
    for (int kt = 0; kt < 4; ++kt)
      #pragma unroll
      for (int jt = 0; jt < 8; ++jt)
        acc[jt] = __builtin_amdgcn_mfma_f32_16x16x32_bf16(
            afrag[kt], bfrag[jt][kt], acc[jt], 0, 0, 0);

    #pragma unroll
    for (int jt = 0; jt < 8; ++jt) {
      const int jc = jt * 16 + lr;
      #pragma unroll
      for (int r = 0; r < 4; ++r) {
        float vv = acc[jt][r] + bias[jt];
        if (w == 3) vv = sigmoidf_(vv);
        const int pos = pos0 + it * 16 + lg * 4 + r;
        size_t off;
        if (w == 3) {
          off = (size_t)pos * 128 + jc;
        } else {
          const int n = pos >> 8, ii = pos & 255, h = jt >> 1, ch = (jt & 1) * 16 + lr;
          off = ((size_t)((n * 4 + h) * 256 + ii)) * 32 + ch;
        }
        outp[off] = f2bf(vv);
      }
    }
  }
}

// ---------------------------------------------------------------------------
// K2: attention per (h,n), MFMA. Swapped QK^T (S^T = K·Q^T) -> lane-local
//   row-sum; max-free softmax; normalized P bounced via swizzled LDS; PV.
//   Writes normalized, UNGATED O as bf16 [pos][128] (gate applied in K3).
// ---------------------------------------------------------------------------
__global__ __launch_bounds__(256) void attn_mfma(
    const unsigned short* __restrict__ q, const unsigned short* __restrict__ k,
    const unsigned short* __restrict__ v, unsigned short* __restrict__ o_ws)
{
  __shared__ unsigned short kl[Lc * DCc];   // 16 KB [j][ch] swizzled
  __shared__ unsigned short vt[DCc * Lc];   // 16 KB [ch][j] swizzled
  __shared__ unsigned short pl[4][16 * Lc]; // 4 x 8 KB per-wave P [i][j] swizzled

  const int t = threadIdx.x;
  const int h = blockIdx.x, n = blockIdx.y;
  const int w = t >> 6, l = t & 63, lr = l & 15, lg = l >> 4;
  const size_t base = ((size_t)(n * Hc + h)) * (Lc * DCc);

  // ---- stage K: [j][ch] bf16, swizzle byte ^= (j&7)<<4 ----
  #pragma unroll
  for (int pass = 0; pass < 4; ++pass) {
    const int cid = pass * 256 + t;           // 1024 x 16B chunks
    const int j = cid >> 2, c = cid & 3;
    bf16x8 kk = *reinterpret_cast<const bf16x8*>(&k[base + (size_t)j * 32 + c * 8]);
    int byte = j * 64 + c * 16;
    byte ^= ((j & 7) << 4);
    *reinterpret_cast<bf16x8*>(reinterpret_cast<char*>(kl) + byte) = kk;
  }
  // ---- stage V transposed: vt[ch][j], swizzle byte ^= (ch&7)<<4 ----
  #pragma unroll
  for (int pass = 0; pass < 2; ++pass) {
    const int cid = pass * 256 + t;           // jp 0..127, c 0..3
    const int jp = cid >> 2, c = cid & 3;
    const int j0 = jp * 2;
    bf16x8 v0 = *reinterpret_cast<const bf16x8*>(&v[base + (size_t)j0 * 32 + c * 8]);
    bf16x8 v1 = *reinterpret_cast<const bf16x8*>(&v[base + (size_t)(j0 + 1) * 32 + c * 8]);
    #pragma unroll
    for (int e = 0; e < 8; ++e) {
      const int ch = c * 8 + e;
      unsigned word = ((unsigned)(unsigned short)v0[e]) |
                      (((unsigned)(unsigned short)v1[e]) << 16);
      int byte = ch * 512 + j0 * 2;
      byte ^= ((ch & 7) << 4);
      *reinterpret_cast<unsigned*>(reinterpret_cast<char*>(vt) + byte) = word;
    }
  }
  __syncthreads();

  char* plb = reinterpret_cast<char*>(&pl[w][0]);
  const char* klb = reinterpret_cast<const char*>(kl);
  const char* vtb = reinterpret_cast<const char*>(vt);

  #pragma unroll 1
  for (int it = 0; it < 4; ++it) {
    const int ib = w * 64 + it * 16;          // this wave's 16 query rows

    // Q B-frag: col i = lr, k(ch) = lg*8.. (direct from global, 1 KB/wave)
    bf16x8 qfrag = *reinterpret_cast<const bf16x8*>(
        &q[base + (size_t)(ib + lr) * 32 + lg * 8]);

    // ---- S^T = K · Q^T : 16 j-tiles ----
    f32x4 sacc[16];
    #pragma unroll
    for (int jt = 0; jt < 16; ++jt) sacc[jt] = (f32x4){0.f, 0.f, 0.f, 0.f};
    #pragma unroll
    for (int jt = 0; jt < 16; ++jt) {
      int byte = (jt * 16 + lr) * 64 + lg * 16;
      byte ^= ((lr & 7) << 4);
      bf16x8 kf = *reinterpret_cast<const bf16x8*>(klb + byte);
      sacc[jt] = __builtin_amdgcn_mfma_f32_16x16x32_bf16(kf, qfrag, sacc[jt], 0, 0, 0);
    }

    // ---- max-free softmax: exp in place, lane-local row sum ----
    float psum = 0.f;
    #pragma unroll
    for (int jt = 0; jt < 16; ++jt)
      #pragma unroll
      for (int r = 0; r < 4; ++r) {
        const float e = __expf(sacc[jt][r]);
        sacc[jt][r] = e;
        psum += e;
      }
    psum += __shfl_xor(psum, 16);
    psum += __shfl_xor(psum, 32);
    const float rl = 1.0f / psum;

    // ---- pack normalized P (bf16) into per-wave swizzled LDS ----
    #pragma unroll
    for (int jt = 0; jt < 16; ++jt) {
      unsigned w0 = (unsigned)f2bf(sacc[jt][0] * rl) |
                    ((unsigned)f2bf(sacc[jt][1] * rl) << 16);
      unsigned w1 = (unsigned)f2bf(sacc[jt][2] * rl) |
                    ((unsigned)f2bf(sacc[jt][3] * rl) << 16);
      int byte = lr * 512 + (jt * 16 + lg * 4) * 2;
      byte ^= ((lr & 7) << 4);
      uint2 pk; pk.x = w0; pk.y = w1;
      *reinterpret_cast<uint2*>(plb + byte) = pk;
    }
    asm volatile("s_waitcnt lgkmcnt(0)" ::: "memory");
    __builtin_amdgcn_sched_barrier(0);

    // ---- O = P · V ----
    f32x4 oacc[2];
    oacc[0] = (f32x4){0.f, 0.f, 0.f, 0.f};
    oacc[1] = (f32x4){0.f, 0.f, 0.f, 0.f};
    #pragma unroll
    for (int kt = 0; kt < 8; ++kt) {
      int pbyte = lr * 512 + (kt * 64 + lg * 16);
      pbyte ^= ((lr & 7) << 4);
      bf16x8 pf = *reinterpret_cast<const bf16x8*>(plb + pbyte);
      #pragma unroll
      for (int cht = 0; cht < 2; ++cht) {
        const int ch = cht * 16 + lr;
        int vbyte = ch * 512 + (kt * 64 + lg * 16);
        vbyte ^= ((ch & 7) << 4);
        bf16x8 vf = *reinterpret_cast<const bf16x8*>(vtb + vbyte);
        oacc[cht] = __builtin_amdgcn_mfma_f32_16x16x32_bf16(pf, vf, oacc[cht], 0, 0, 0);
      }
    }

    // ---- store O bf16 to [pos][128] (32B-contiguous per 16-lane group) ----
    #pragma unroll
    for (int cht = 0; cht < 2; ++cht)
      #pragma unroll
      for (int r = 0; r < 4; ++r) {
        const int i = ib + lg * 4 + r;
        const size_t off = ((size_t)(n * Lc + i)) * 128 + h * 32 + cht * 16 + lr;
        o_ws[off] = f2bf(oacc[cht][r]);
      }
  }
}

// ---------------------------------------------------------------------------
// K3: out^T = w2^T · (o·g)^T  -> out[c][pos] fp32, coalesced along pos.
// ---------------------------------------------------------------------------
__global__ __launch_bounds__(256) void outproj_mfma(
    const unsigned short* __restrict__ o_ws, const unsigned short* __restrict__ g_ws,
    const unsigned short* __restrict__ w2T, const float* __restrict__ b2,
    float* __restrict__ out)
{
  const int t = threadIdx.x;
  const int w = t >> 6, l = t & 63, lr = l & 15, lg = l >> 4;
  const int pos = blockIdx.x * 64 + w * 16 + lr;

  // B-frags: zo^T (col pos = lr, k contiguous) = row-major o,g reads + gate
  bf16x8 zb[4];
  #pragma unroll
  for (int kt = 0; kt < 4; ++kt) {
    const size_t off = (size_t)pos * 128 + kt * 32 + lg * 8;
    bf16x8 ov = *reinterpret_cast<const bf16x8*>(&o_ws[off]);
    bf16x8 gv = *reinterpret_cast<const bf16x8*>(&g_ws[off]);
    bf16x8 zv;
    #pragma unroll
    for (int e = 0; e < 8; ++e)
      zv[e] = (short)f2bf(bf2f((unsigned short)ov[e]) * bf2f((unsigned short)gv[e]));
    zb[kt] = zv;
  }

  #pragma unroll
  for (int ct = 0; ct < 8; ++ct) {
    f32x4 acc = (f32x4){0.f, 0.f, 0.f, 0.f};
    #pragma unroll
    for (int kt = 0; kt < 4; ++kt) {
      bf16x8 af = *reinterpret_cast<const bf16x8*>(
          &w2T[(size_t)(ct * 16 + lr) * 128 + kt * 32 + lg * 8]);
      acc = __builtin_amdgcn_mfma_f32_16x16x32_bf16(af, zb[kt], acc, 0, 0, 0);
    }
    #pragma unroll
    for (int r = 0; r < 4; ++r) {
      const int c = ct * 16 + lg * 4 + r;
      out[(size_t)c * NPOSc + pos] = acc[r] + b2[c];
    }
  }
}

// ---------------------------------------------------------------------------
extern "C" void kernel_launch(void* const* d_in, const int* in_sizes, int n_in,
                              void* d_out, int out_size, void* d_ws, size_t ws_size,
                              hipStream_t stream) {
  const float* z   = (const float*)d_in[0];
  const float* lnw = (const float*)d_in[1];
  const float* lnb = (const float*)d_in[2];
  const float* wq  = (const float*)d_in[3];
  const float* bq  = (const float*)d_in[4];
  const float* wk  = (const float*)d_in[5];
  const float* bk  = (const float*)d_in[6];
  const float* wv  = (const float*)d_in[7];
  const float* bv  = (const float*)d_in[8];
  const float* wg  = (const float*)d_in[9];
  const float* bg  = (const float*)d_in[10];
  const float* w2  = (const float*)d_in[11];
  const float* b2  = (const float*)d_in[12];
  float* out = (float*)d_out;

  const size_t S = (size_t)NPOSc * DHCc;        // 8388608 elements
  unsigned short* ws = (unsigned short*)d_ws;
  unsigned short* q_ws = ws;                    // [n][h][i][ch]
  unsigned short* k_ws = ws + S;
  unsigned short* v_ws = ws + 2 * S;
  unsigned short* g_ws = ws + 3 * S;            // [pos][128] sigmoid applied
  unsigned short* o_ws = ws + 4 * S;            // [pos][128] normalized, ungated
  unsigned short* wT   = ws + 5 * S;            // 5 x 16384 bf16 weights
  float* mus  = (float*)(ws + 6 * S);           // 65536 f32
  float* rsts = mus + NPOSc;                    // 65536 f32

  prep_stats<<<261, 256, 0, stream>>>(wq, wk, wv, wg, w2, z, wT, mus, rsts);
  ln_qkvg_mfma<<<NPOSc / 128, 256, 0, stream>>>(
      z, lnw, lnb, wT, mus, rsts, bq, bk, bv, bg, q_ws, k_ws, v_ws, g_ws);
  attn_mfma<<<dim3(Hc, Lc), 256, 0, stream>>>(q_ws, k_ws, v_ws, o_ws);
  outproj_mfma<<<NPOSc / 64, 256, 0, stream>>>(
      o_ws, g_ws, wT + 4 * (DZc * DHCc), b2, out);
}

// Round 5
// 119.722 us; speedup vs baseline: 1.3222x; 1.3222x over previous
//
#include <hip/hip_runtime.h>
#include <cstdint>
#include <cstddef>

#define DZc   128
#define Lc    256
#define Hc    4
#define DCc   32
#define DHCc  128
#define NPOSc (Lc * Lc)

typedef __attribute__((ext_vector_type(8))) short bf16x8;
typedef __attribute__((ext_vector_type(4))) short bf16x4;
typedef __attribute__((ext_vector_type(4))) float f32x4;

static __device__ __forceinline__ unsigned short f2bf(float f) {
  unsigned u = __float_as_uint(f);
  u += 0x7FFFu + ((u >> 16) & 1u);     // round-to-nearest-even
  return (unsigned short)(u >> 16);
}
static __device__ __forceinline__ float bf2f(unsigned short h) {
  return __uint_as_float(((unsigned)h) << 16);
}
static __device__ __forceinline__ float sigmoidf_(float x) {
  return 1.0f / (1.0f + __expf(-x));
}

// ---------------------------------------------------------------------------
// prep+stats: blocks 0..4 transpose weights fp32 [k][j] -> bf16 [j][k]
// (q-scale folded into wq; slot 4 = w2 -> w2T[c][k]).
// Blocks 5..260: per-position LayerNorm stats (mu, rsqrt) over DZ.
// ---------------------------------------------------------------------------
__global__ __launch_bounds__(256) void prep_stats(
    const float* __restrict__ wq, const float* __restrict__ wk,
    const float* __restrict__ wv, const float* __restrict__ wg,
    const float* __restrict__ w2, const float* __restrict__ z,
    unsigned short* __restrict__ wT,
    float* __restrict__ mus, float* __restrict__ rsts)
{
  const int b = blockIdx.x;
  const int t = threadIdx.x;
  if (b < 5) {
    const float* src = (b == 0) ? wq : (b == 1) ? wk : (b == 2) ? wv : (b == 3) ? wg : w2;
    unsigned short* dst = wT + (size_t)b * (DZc * DHCc);
    const float scale = (b == 0) ? 0.17677669529663687f : 1.0f;  // sqrt(1/32)
    for (int p = 0; p < 64; ++p) {
      const int idx = p * 256 + t;             // 16384 elements
      const int kk = idx >> 7, j = idx & 127;  // src[kk][j]
      dst[j * 128 + kk] = f2bf(src[idx] * scale);
    }
  } else {
    const int pos = (b - 5) * 256 + t;
    float s = 0.f, s2 = 0.f;
    #pragma unroll 8
    for (int c = 0; c < DZc; ++c) {
      const float x = z[(size_t)c * NPOSc + pos];
      s += x; s2 += x * x;
    }
    const float mu = s * (1.0f / DZc);
    const float var = s2 * (1.0f / DZc) - mu * mu;
    mus[pos]  = mu;
    rsts[pos] = rsqrtf(var + 1e-5f);
  }
}

// ---------------------------------------------------------------------------
// K1 v3: LN-apply + 4 projections via MFMA. 128 pos/block, LDS = znl only.
//   NO min-waves launch-bound (round-4 lesson: capping VGPR=64 spilled
//   bfrag to scratch -> 172MB FETCH). B-frags split into two j-half passes
//   so live regs ~= 64(bfrag)+16(acc)+16(afrag) -> no spill.
//   v output written TRANSPOSED [n][h][ch][ii] with 8B packed stores.
// ---------------------------------------------------------------------------
__global__ __launch_bounds__(256) void ln_qkvg_mfma(
    const float* __restrict__ z, const float* __restrict__ lnw, const float* __restrict__ lnb,
    const unsigned short* __restrict__ wT,
    const float* __restrict__ mus, const float* __restrict__ rsts,
    const float* __restrict__ bq, const float* __restrict__ bk,
    const float* __restrict__ bv, const float* __restrict__ bg,
    unsigned short* __restrict__ q_ws, unsigned short* __restrict__ k_ws,
    unsigned short* __restrict__ v_ws, unsigned short* __restrict__ g_ws)
{
  __shared__ unsigned short znl[128 * DZc];   // 32 KB bf16 [i][c], XOR-swizzled

  const int t = threadIdx.x;
  const int pos0 = blockIdx.x * 128;
  const int n = pos0 >> 8;        // constant per block
  const int w  = t >> 6;          // wave = weight index (0=q,1=k,2=v,3=g)
  const int l  = t & 63;
  const int lr = l & 15;
  const int lg = l >> 4;

  const unsigned short* wTw = wT + (size_t)w * (DZc * DHCc);
  const float* bptr = (w == 0) ? bq : (w == 1) ? bk : (w == 2) ? bv : bg;
  float bias[8];
  #pragma unroll
  for (int jt = 0; jt < 8; ++jt) {
    float bb = bptr[jt * 16 + lr];
    if (w == 0) bb *= 0.17677669529663687f;
    bias[jt] = bb;
  }

  // ---- Phase A: LN apply, pack, swizzled b128 znl writes ----
  {
    const int i = t & 127;                  // local pos (1 per thread)
    const int cbase = (t >> 7) * 64;        // wave-uniform c half
    const int gpos = pos0 + i;
    const float mu = mus[gpos], rs = rsts[gpos];
    #pragma unroll
    for (int cc = 0; cc < 64; cc += 8) {
      unsigned short pk[8];
      #pragma unroll
      for (int e = 0; e < 8; ++e) {
        const int c = cbase + cc + e;
        const float x = z[(size_t)c * NPOSc + gpos];
        pk[e] = f2bf((x - mu) * rs * lnw[c] + lnb[c]);
      }
      int byte = i * 256 + (cbase + cc) * 2;
      byte ^= ((i & 7) << 4);
      *reinterpret_cast<bf16x8*>(reinterpret_cast<char*>(znl) + byte) =
          *reinterpret_cast<const bf16x8*>(pk);
    }
  }
  __syncthreads();

  // ---- Phase B: GEMM in two j-half passes (bfrag live = 64 VGPRs) ----
  unsigned short* outp = (w == 0) ? q_ws : (w == 1) ? k_ws : (w == 2) ? v_ws : g_ws;
  const char* znlb = reinterpret_cast<const char*>(znl);

  #pragma unroll 1
  for (int jh = 0; jh < 2; ++jh) {
    bf16x8 bfrag[4][4];
    #pragma unroll
    for (int jt = 0; jt < 4; ++jt)
      #pragma unroll
      for (int kt = 0; kt < 4; ++kt)
        bfrag[jt][kt] = *reinterpret_cast<const bf16x8*>(
            &wTw[(size_t)(jh * 64 + jt * 16 + lr) * 128 + kt * 32 + lg * 8]);

    #pragma unroll 1
    for (int it = 0; it < 8; ++it) {
      bf16x8 afrag[4];
      #pragma unroll
      for (int kt = 0; kt < 4; ++kt) {
        const int i = it * 16 + lr;
        int byte = i * 256 + (kt * 64 + lg * 16);
        byte ^= ((i & 7) << 4);
        afrag[kt] = *reinterpret_cast<const bf16x8*>(znlb + byte);
      }
      f32x4 acc[4];
      #pragma unroll
      for (int jt = 0; jt < 4; ++jt) acc[jt] = (f32x4){0.f, 0.f, 0.f, 0.f};
      #pragma unroll
      for (int kt = 0; kt < 4; ++kt)
        #pragma unroll
        for (int jt = 0; jt < 4; ++jt)
          acc[jt] = __builtin_amdgcn_mfma_f32_16x16x32_bf16(
              afrag[kt], bfrag[jt][kt], acc[jt], 0, 0, 0);

      const int ii0 = (pos0 & 255) + it * 16 + lg * 4;
      #pragma unroll
      for (int jt = 0; jt < 4; ++jt) {
        const int jc = jh * 64 + jt * 16 + lr;
        const float bb = bias[jh * 4 + jt];
        if (w == 2) {
          // v: transposed layout [n*4+h][ch][ii], 4 consecutive ii -> 8B store
          const int h = jc >> 5, ch = jc & 31;
          unsigned short pk[4];
          #pragma unroll
          for (int r = 0; r < 4; ++r) pk[r] = f2bf(acc[jt][r] + bb);
          *reinterpret_cast<bf16x4*>(
              &outp[((size_t)(n * 4 + h) * 32 + ch) * 256 + ii0]) =
              *reinterpret_cast<const bf16x4*>(pk);
        } else {
          #pragma unroll
          for (int r = 0; r < 4; ++r) {
            float vv = acc[jt][r] + bb;
            if (w == 3) vv = sigmoidf_(vv);
            size_t off;
            if (w == 3) {
              off = (size_t)(pos0 + it * 16 + lg * 4 + r) * 128 + jc;
            } else {
              const int h = jc >> 5, ch = jc & 31;
              off = ((size_t)(n * 4 + h) * 256 + ii0 + r) * 32 + ch;
            }
            outp[off] = f2bf(vv);
          }
        }
      }
    }
  }
}

// ---------------------------------------------------------------------------
// K2: attention per (h,n), MFMA. Swapped QK^T (S^T = K·Q^T) -> lane-local
//   row-sum; max-free softmax; normalized P bounced via swizzled LDS; PV.
//   V arrives pre-transposed [n][h][ch][ii] -> staging is a straight copy.
//   Writes normalized, UNGATED O as bf16 [pos][128] (gate applied in K3).
// ---------------------------------------------------------------------------
__global__ __launch_bounds__(256) void attn_mfma(
    const unsigned short* __restrict__ q, const unsigned short* __restrict__ k,
    const unsigned short* __restrict__ v, unsigned short* __restrict__ o_ws)
{
  __shared__ unsigned short kl[Lc * DCc];   // 16 KB [j][ch] swizzled
  __shared__ unsigned short vt[DCc * Lc];   // 16 KB [ch][j] swizzled
  __shared__ unsigned short pl[4][16 * Lc]; // 4 x 8 KB per-wave P [i][j] swizzled

  const int t = threadIdx.x;
  const int h = blockIdx.x, n = blockIdx.y;
  const int w = t >> 6, l = t & 63, lr = l & 15, lg = l >> 4;
  const size_t base = ((size_t)(n * Hc + h)) * (Lc * DCc);

  // ---- stage K: [j][ch] bf16, swizzle byte ^= (j&7)<<4 ----
  #pragma unroll
  for (int pass = 0; pass < 4; ++pass) {
    const int cid = pass * 256 + t;           // 1024 x 16B chunks
    const int j = cid >> 2, c = cid & 3;
    bf16x8 kk = *reinterpret_cast<const bf16x8*>(&k[base + (size_t)j * 32 + c * 8]);
    int byte = j * 64 + c * 16;
    byte ^= ((j & 7) << 4);
    *reinterpret_cast<bf16x8*>(reinterpret_cast<char*>(kl) + byte) = kk;
  }
  // ---- stage V (pre-transposed): straight copy, swizzle byte ^= (ch&7)<<4 ----
  #pragma unroll
  for (int pass = 0; pass < 4; ++pass) {
    const int cid = pass * 256 + t;           // 1024 x 16B chunks
    const int ch = cid >> 5, c = cid & 31;
    bf16x8 vv = *reinterpret_cast<const bf16x8*>(&v[base + (size_t)ch * 256 + c * 8]);
    int byte = ch * 512 + c * 16;
    byte ^= ((ch & 7) << 4);
    *reinterpret_cast<bf16x8*>(reinterpret_cast<char*>(vt) + byte) = vv;
  }
  __syncthreads();

  char* plb = reinterpret_cast<char*>(&pl[w][0]);
  const char* klb = reinterpret_cast<const char*>(kl);
  const char* vtb = reinterpret_cast<const char*>(vt);

  #pragma unroll 1
  for (int it = 0; it < 4; ++it) {
    const int ib = w * 64 + it * 16;          // this wave's 16 query rows

    // Q B-frag: col i = lr, k(ch) = lg*8.. (direct from global, 1 KB/wave)
    bf16x8 qfrag = *reinterpret_cast<const bf16x8*>(
        &q[base + (size_t)(ib + lr) * 32 + lg * 8]);

    // ---- S^T = K · Q^T : 16 j-tiles ----
    f32x4 sacc[16];
    #pragma unroll
    for (int jt = 0; jt < 16; ++jt) sacc[jt] = (f32x4){0.f, 0.f, 0.f, 0.f};
    #pragma unroll
    for (int jt = 0; jt < 16; ++jt) {
      int byte = (jt * 16 + lr) * 64 + lg * 16;
      byte ^= ((lr & 7) << 4);
      bf16x8 kf = *reinterpret_cast<const bf16x8*>(klb + byte);
      sacc[jt] = __builtin_amdgcn_mfma_f32_16x16x32_bf16(kf, qfrag, sacc[jt], 0, 0, 0);
    }

    // ---- max-free softmax: exp in place, lane-local row sum ----
    float psum = 0.f;
    #pragma unroll
    for (int jt = 0; jt < 16; ++jt)
      #pragma unroll
      for (int r = 0; r < 4; ++r) {
        const float e = __expf(sacc[jt][r]);
        sacc[jt][r] = e;
        psum += e;
      }
    psum += __shfl_xor(psum, 16);
    psum += __shfl_xor(psum, 32);
    const float rl = 1.0f / psum;

    // ---- pack normalized P (bf16) into per-wave swizzled LDS ----
    #pragma unroll
    for (int jt = 0; jt < 16; ++jt) {
      unsigned w0 = (unsigned)f2bf(sacc[jt][0] * rl) |
                    ((unsigned)f2bf(sacc[jt][1] * rl) << 16);
      unsigned w1 = (unsigned)f2bf(sacc[jt][2] * rl) |
                    ((unsigned)f2bf(sacc[jt][3] * rl) << 16);
      int byte = lr * 512 + (jt * 16 + lg * 4) * 2;
      byte ^= ((lr & 7) << 4);
      uint2 pk; pk.x = w0; pk.y = w1;
      *reinterpret_cast<uint2*>(plb + byte) = pk;
    }
    asm volatile("s_waitcnt lgkmcnt(0)" ::: "memory");
    __builtin_amdgcn_sched_barrier(0);

    // ---- O = P · V ----
    f32x4 oacc[2];
    oacc[0] = (f32x4){0.f, 0.f, 0.f, 0.f};
    oacc[1] = (f32x4){0.f, 0.f, 0.f, 0.f};
    #pragma unroll
    for (int kt = 0; kt < 8; ++kt) {
      int pbyte = lr * 512 + (kt * 64 + lg * 16);
      pbyte ^= ((lr & 7) << 4);
      bf16x8 pf = *reinterpret_cast<const bf16x8*>(plb + pbyte);
      #pragma unroll
      for (int cht = 0; cht < 2; ++cht) {
        const int ch = cht * 16 + lr;
        int vbyte = ch * 512 + (kt * 64 + lg * 16);
        vbyte ^= ((ch & 7) << 4);
        bf16x8 vf = *reinterpret_cast<const bf16x8*>(vtb + vbyte);
        oacc[cht] = __builtin_amdgcn_mfma_f32_16x16x32_bf16(pf, vf, oacc[cht], 0, 0, 0);
      }
    }

    // ---- store O bf16 to [pos][128] (32B-contiguous per 16-lane group) ----
    #pragma unroll
    for (int cht = 0; cht < 2; ++cht)
      #pragma unroll
      for (int r = 0; r < 4; ++r) {
        const int i = ib + lg * 4 + r;
        const size_t off = ((size_t)(n * Lc + i)) * 128 + h * 32 + cht * 16 + lr;
        o_ws[off] = f2bf(oacc[cht][r]);
      }
  }
}

// ---------------------------------------------------------------------------
// K3: out^T = w2^T · (o·g)^T  -> out[c][pos] fp32, coalesced along pos.
// ---------------------------------------------------------------------------
__global__ __launch_bounds__(256) void outproj_mfma(
    const unsigned short* __restrict__ o_ws, const unsigned short* __restrict__ g_ws,
    const unsigned short* __restrict__ w2T, const float* __restrict__ b2,
    float* __restrict__ out)
{
  const int t = threadIdx.x;
  const int w = t >> 6, l = t & 63, lr = l & 15, lg = l >> 4;
  const int pos = blockIdx.x * 64 + w * 16 + lr;

  // B-frags: zo^T (col pos = lr, k contiguous) = row-major o,g reads + gate
  bf16x8 zb[4];
  #pragma unroll
  for (int kt = 0; kt < 4; ++kt) {
    const size_t off = (size_t)pos * 128 + kt * 32 + lg * 8;
    bf16x8 ov = *reinterpret_cast<const bf16x8*>(&o_ws[off]);
    bf16x8 gv = *reinterpret_cast<const bf16x8*>(&g_ws[off]);
    bf16x8 zv;
    #pragma unroll
    for (int e = 0; e < 8; ++e)
      zv[e] = (short)f2bf(bf2f((unsigned short)ov[e]) * bf2f((unsigned short)gv[e]));
    zb[kt] = zv;
  }

  #pragma unroll
  for (int ct = 0; ct < 8; ++ct) {
    f32x4 acc = (f32x4){0.f, 0.f, 0.f, 0.f};
    #pragma unroll
    for (int kt = 0; kt < 4; ++kt) {
      bf16x8 af = *reinterpret_cast<const bf16x8*>(
          &w2T[(size_t)(ct * 16 + lr) * 128 + kt * 32 + lg * 8]);
      acc = __builtin_amdgcn_mfma_f32_16x16x32_bf16(af, zb[kt], acc, 0, 0, 0);
    }
    #pragma unroll
    for (int r = 0; r < 4; ++r) {
      const int c = ct * 16 + lg * 4 + r;
      out[(size_t)c * NPOSc + pos] = acc[r] + b2[c];
    }
  }
}

// ---------------------------------------------------------------------------
extern "C" void kernel_launch(void* const* d_in, const int* in_sizes, int n_in,
                              void* d_out, int out_size, void* d_ws, size_t ws_size,
                              hipStream_t stream) {
  const float* z   = (const float*)d_in[0];
  const float* lnw = (const float*)d_in[1];
  const float* lnb = (const float*)d_in[2];
  const float* wq  = (const float*)d_in[3];
  const float* bq  = (const float*)d_in[4];
  const float* wk  = (const float*)d_in[5];
  const float* bk  = (const float*)d_in[6];
  const float* wv  = (const float*)d_in[7];
  const float* bv  = (const float*)d_in[8];
  const float* wg  = (const float*)d_in[9];
  const float* bg  = (const float*)d_in[10];
  const float* w2  = (const float*)d_in[11];
  const float* b2  = (const float*)d_in[12];
  float* out = (float*)d_out;

  const size_t S = (size_t)NPOSc * DHCc;        // 8388608 elements
  unsigned short* ws = (unsigned short*)d_ws;
  unsigned short* q_ws = ws;                    // [n][h][i][ch]
  unsigned short* k_ws = ws + S;                // [n][h][j][ch]
  unsigned short* v_ws = ws + 2 * S;            // [n][h][ch][ii] (transposed)
  unsigned short* g_ws = ws + 3 * S;            // [pos][128] sigmoid applied
  unsigned short* o_ws = ws + 4 * S;            // [pos][128] normalized, ungated
  unsigned short* wT   = ws + 5 * S;            // 5 x 16384 bf16 weights
  float* mus  = (float*)(ws + 6 * S);           // 65536 f32
  float* rsts = mus + NPOSc;                    // 65536 f32

  prep_stats<<<261, 256, 0, stream>>>(wq, wk, wv, wg, w2, z, wT, mus, rsts);
  ln_qkvg_mfma<<<NPOSc / 128, 256, 0, stream>>>(
      z, lnw, lnb, wT, mus, rsts, bq, bk, bv, bg, q_ws, k_ws, v_ws, g_ws);
  attn_mfma<<<dim3(Hc, Lc), 256, 0, stream>>>(q_ws, k_ws, v_ws, o_ws);
  outproj_mfma<<<NPOSc / 64, 256, 0, stream>>>(
      o_ws, g_ws, wT + 4 * (DZc * DHCc), b2, out);
}

// Round 7
// 114.059 us; speedup vs baseline: 1.3879x; 1.0497x over previous
//
#include <hip/hip_runtime.h>
#include <cstdint>
#include <cstddef>

#define DZc   128
#define Lc    256
#define Hc    4
#define DCc   32
#define DHCc  128
#define NPOSc (Lc * Lc)

typedef __attribute__((ext_vector_type(8))) short bf16x8;
typedef __attribute__((ext_vector_type(4))) short bf16x4;
typedef __attribute__((ext_vector_type(4))) float f32x4;

static __device__ __forceinline__ unsigned short f2bf(float f) {
  unsigned u = __float_as_uint(f);
  u += 0x7FFFu + ((u >> 16) & 1u);     // round-to-nearest-even
  return (unsigned short)(u >> 16);
}
static __device__ __forceinline__ float bf2f(unsigned short h) {
  return __uint_as_float(((unsigned)h) << 16);
}
static __device__ __forceinline__ float sigmoidf_(float x) {
  return 1.0f / (1.0f + __expf(-x));
}

// ---------------------------------------------------------------------------
// prep+stats: blocks 0..4 transpose weights fp32 [k][j] -> bf16 [j][k]
// (q-scale folded into wq; slot 4 = w2 -> w2T[c][k]).
// Blocks 5..260: per-position LayerNorm stats (mu, rsqrt) over DZ.
// ---------------------------------------------------------------------------
__global__ __launch_bounds__(256) void prep_stats(
    const float* __restrict__ wq, const float* __restrict__ wk,
    const float* __restrict__ wv, const float* __restrict__ wg,
    const float* __restrict__ w2, const float* __restrict__ z,
    unsigned short* __restrict__ wT,
    float* __restrict__ mus, float* __restrict__ rsts)
{
  const int b = blockIdx.x;
  const int t = threadIdx.x;
  if (b < 5) {
    const float* src = (b == 0) ? wq : (b == 1) ? wk : (b == 2) ? wv : (b == 3) ? wg : w2;
    unsigned short* dst = wT + (size_t)b * (DZc * DHCc);
    const float scale = (b == 0) ? 0.17677669529663687f : 1.0f;  // sqrt(1/32)
    for (int p = 0; p < 64; ++p) {
      const int idx = p * 256 + t;             // 16384 elements
      const int kk = idx >> 7, j = idx & 127;  // src[kk][j]
      dst[j * 128 + kk] = f2bf(src[idx] * scale);
    }
  } else {
    const int pos = (b - 5) * 256 + t;
    float s = 0.f, s2 = 0.f;
    #pragma unroll 8
    for (int c = 0; c < DZc; ++c) {
      const float x = z[(size_t)c * NPOSc + pos];
      s += x; s2 += x * x;
    }
    const float mu = s * (1.0f / DZc);
    const float var = s2 * (1.0f / DZc) - mu * mu;
    mus[pos]  = mu;
    rsts[pos] = rsqrtf(var + 1e-5f);
  }
}

// ---------------------------------------------------------------------------
// K1 v4: LN-apply + 4 projections via MFMA. 128 pos/block, LDS = znl only.
//   Phase A: float4 z loads (pos-quad per lane), conflict-free swizzled
//   b128 znl writes. Phase B: q/k/g waves use SWAPPED operands
//   (mfma(w, zn) -> D[jc][pos]) so stores are packed 8B bf16x4 along ch;
//   v wave keeps D[pos][jc] for its transposed [ch][ii] 8B stores.
// ---------------------------------------------------------------------------
__global__ __launch_bounds__(256) void ln_qkvg_mfma(
    const float* __restrict__ z, const float* __restrict__ lnw, const float* __restrict__ lnb,
    const unsigned short* __restrict__ wT,
    const float* __restrict__ mus, const float* __restrict__ rsts,
    const float* __restrict__ bq, const float* __restrict__ bk,
    const float* __restrict__ bv, const float* __restrict__ bg,
    unsigned short* __restrict__ q_ws, unsigned short* __restrict__ k_ws,
    unsigned short* __restrict__ v_ws, unsigned short* __restrict__ g_ws)
{
  __shared__ unsigned short znl[128 * DZc];   // 32 KB bf16 [i][c], XOR-swizzled

  const int t = threadIdx.x;
  const int pos0 = blockIdx.x * 128;
  const int n = pos0 >> 8;        // constant per block
  const int w  = t >> 6;          // wave = weight index (0=q,1=k,2=v,3=g)
  const int l  = t & 63;
  const int lr = l & 15;
  const int lg = l >> 4;

  const unsigned short* wTw = wT + (size_t)w * (DZc * DHCc);
  const float* bptr = (w == 0) ? bq : (w == 1) ? bk : (w == 2) ? bv : bg;
  const float qscale = 0.17677669529663687f;

  // v-wave bias (per jc = jt*16+lr, lr baked in)
  float biasv[8];
  #pragma unroll
  for (int jt = 0; jt < 8; ++jt) biasv[jt] = bptr[jt * 16 + lr];

  // ---- Phase A: LN apply, float4 z loads, conflict-free swizzled writes ----
  {
    const int pq = t >> 3;          // 0..31 pos-quad
    const int cg = t & 7;           // 0..7 c-group (16 c each)
    const int gp = pos0 + pq * 4;
    const float4 mu4 = *reinterpret_cast<const float4*>(&mus[gp]);
    const float4 rs4 = *reinterpret_cast<const float4*>(&rsts[gp]);
    const float mu[4] = {mu4.x, mu4.y, mu4.z, mu4.w};
    const float rs[4] = {rs4.x, rs4.y, rs4.z, rs4.w};
    #pragma unroll
    for (int sub = 0; sub < 2; ++sub) {
      const int cb = cg * 16 + sub * 8;
      unsigned short pk[4][8];
      #pragma unroll
      for (int cc = 0; cc < 8; ++cc) {
        const int c = cb + cc;
        const float lw = lnw[c], lb = lnb[c];
        const float4 zv = *reinterpret_cast<const float4*>(&z[(size_t)c * NPOSc + gp]);
        pk[0][cc] = f2bf((zv.x - mu[0]) * rs[0] * lw + lb);
        pk[1][cc] = f2bf((zv.y - mu[1]) * rs[1] * lw + lb);
        pk[2][cc] = f2bf((zv.z - mu[2]) * rs[2] * lw + lb);
        pk[3][cc] = f2bf((zv.w - mu[3]) * rs[3] * lw + lb);
      }
      #pragma unroll
      for (int e = 0; e < 4; ++e) {
        const int i = pq * 4 + e;
        int byte = i * 256 + cb * 2;
        byte ^= ((i & 7) << 4);
        *reinterpret_cast<bf16x8*>(reinterpret_cast<char*>(znl) + byte) =
            *reinterpret_cast<const bf16x8*>(pk[e]);
      }
    }
  }
  __syncthreads();

  // ---- Phase B: GEMM in two j-half passes (bfrag live = 64 VGPRs) ----
  unsigned short* outp = (w == 0) ? q_ws : (w == 1) ? k_ws : (w == 2) ? v_ws : g_ws;
  const char* znlb = reinterpret_cast<const char*>(znl);

  #pragma unroll 1
  for (int jh = 0; jh < 2; ++jh) {
    bf16x8 bfrag[4][4];
    #pragma unroll
    for (int jt = 0; jt < 4; ++jt)
      #pragma unroll
      for (int kt = 0; kt < 4; ++kt)
        bfrag[jt][kt] = *reinterpret_cast<const bf16x8*>(
            &wTw[(size_t)(jh * 64 + jt * 16 + lr) * 128 + kt * 32 + lg * 8]);

    // bias for swapped waves: 4 consecutive jc at jc0 = jh*64+jt*16+lg*4
    float bias4[4][4];
    if (w != 2) {
      #pragma unroll
      for (int jt = 0; jt < 4; ++jt) {
        const float4 bb = *reinterpret_cast<const float4*>(
            &bptr[jh * 64 + jt * 16 + lg * 4]);
        bias4[jt][0] = bb.x; bias4[jt][1] = bb.y;
        bias4[jt][2] = bb.z; bias4[jt][3] = bb.w;
        if (w == 0) {
          #pragma unroll
          for (int r = 0; r < 4; ++r) bias4[jt][r] *= qscale;
        }
      }
    }

    #pragma unroll 1
    for (int it = 0; it < 8; ++it) {
      bf16x8 afrag[4];
      #pragma unroll
      for (int kt = 0; kt < 4; ++kt) {
        const int i = it * 16 + lr;
        int byte = i * 256 + (kt * 64 + lg * 16);
        byte ^= ((i & 7) << 4);
        afrag[kt] = *reinterpret_cast<const bf16x8*>(znlb + byte);
      }
      f32x4 acc[4];
      #pragma unroll
      for (int jt = 0; jt < 4; ++jt) acc[jt] = (f32x4){0.f, 0.f, 0.f, 0.f};

      if (w == 2) {
        // ---- v: D[pos][jc], transposed store [n][h][ch][ii] (8B) ----
        #pragma unroll
        for (int kt = 0; kt < 4; ++kt)
          #pragma unroll
          for (int jt = 0; jt < 4; ++jt)
            acc[jt] = __builtin_amdgcn_mfma_f32_16x16x32_bf16(
                afrag[kt], bfrag[jt][kt], acc[jt], 0, 0, 0);
        const int ii0 = (pos0 & 255) + it * 16 + lg * 4;
        #pragma unroll
        for (int jt = 0; jt < 4; ++jt) {
          const int jc = jh * 64 + jt * 16 + lr;
          const float bb = biasv[jh * 4 + jt];
          const int h = jc >> 5, ch = jc & 31;
          unsigned short pk[4];
          #pragma unroll
          for (int r = 0; r < 4; ++r) pk[r] = f2bf(acc[jt][r] + bb);
          *reinterpret_cast<bf16x4*>(
              &outp[((size_t)(n * 4 + h) * 32 + ch) * 256 + ii0]) =
              *reinterpret_cast<const bf16x4*>(pk);
        }
      } else {
        // ---- q/k/g: SWAPPED -> D[jc][pos], packed 8B stores along ch ----
        #pragma unroll
        for (int kt = 0; kt < 4; ++kt)
          #pragma unroll
          for (int jt = 0; jt < 4; ++jt)
            acc[jt] = __builtin_amdgcn_mfma_f32_16x16x32_bf16(
                bfrag[jt][kt], afrag[kt], acc[jt], 0, 0, 0);
        const int pos = pos0 + it * 16 + lr;
        const int ii  = pos & 255;
        #pragma unroll
        for (int jt = 0; jt < 4; ++jt) {
          const int jc0 = jh * 64 + jt * 16 + lg * 4;
          unsigned short pk[4];
          #pragma unroll
          for (int r = 0; r < 4; ++r) {
            float vv = acc[jt][r] + bias4[jt][r];
            if (w == 3) vv = sigmoidf_(vv);
            pk[r] = f2bf(vv);
          }
          unsigned short* dst;
          if (w == 3) {
            dst = &outp[(size_t)pos * 128 + jc0];
          } else {
            const int h = jc0 >> 5, ch = jc0 & 31;
            dst = &outp[((size_t)(n * 4 + h) * 256 + ii) * 32 + ch];
          }
          *reinterpret_cast<bf16x4*>(dst) = *reinterpret_cast<const bf16x4*>(pk);
        }
      }
    }
  }
}

// ---------------------------------------------------------------------------
// K2: attention per (h,n), MFMA. Swapped QK^T (S^T = K·Q^T) -> lane-local
//   row-sum; max-free softmax; NORMALIZED P packed to LDS (x rl ONCE, here);
//   PV; gate fused: O*g written IN PLACE into g_ws [pos][128] (no extra rl!).
// ---------------------------------------------------------------------------
__global__ __launch_bounds__(256) void attn_mfma(
    const unsigned short* __restrict__ q, const unsigned short* __restrict__ k,
    const unsigned short* __restrict__ v, unsigned short* og_ws)
{
  __shared__ unsigned short kl[Lc * DCc];   // 16 KB [j][ch] swizzled
  __shared__ unsigned short vt[DCc * Lc];   // 16 KB [ch][j] swizzled
  __shared__ unsigned short pl[4][16 * Lc]; // 4 x 8 KB per-wave P [i][j] swizzled

  const int t = threadIdx.x;
  const int h = blockIdx.x, n = blockIdx.y;
  const int w = t >> 6, l = t & 63, lr = l & 15, lg = l >> 4;
  const size_t base = ((size_t)(n * Hc + h)) * (Lc * DCc);

  // ---- stage K: [j][ch] bf16, swizzle byte ^= (j&7)<<4 ----
  #pragma unroll
  for (int pass = 0; pass < 4; ++pass) {
    const int cid = pass * 256 + t;           // 1024 x 16B chunks
    const int j = cid >> 2, c = cid & 3;
    bf16x8 kk = *reinterpret_cast<const bf16x8*>(&k[base + (size_t)j * 32 + c * 8]);
    int byte = j * 64 + c * 16;
    byte ^= ((j & 7) << 4);
    *reinterpret_cast<bf16x8*>(reinterpret_cast<char*>(kl) + byte) = kk;
  }
  // ---- stage V (pre-transposed): straight copy, swizzle byte ^= (ch&7)<<4 ----
  #pragma unroll
  for (int pass = 0; pass < 4; ++pass) {
    const int cid = pass * 256 + t;           // 1024 x 16B chunks
    const int ch = cid >> 5, c = cid & 31;
    bf16x8 vv = *reinterpret_cast<const bf16x8*>(&v[base + (size_t)ch * 256 + c * 8]);
    int byte = ch * 512 + c * 16;
    byte ^= ((ch & 7) << 4);
    *reinterpret_cast<bf16x8*>(reinterpret_cast<char*>(vt) + byte) = vv;
  }
  __syncthreads();

  char* plb = reinterpret_cast<char*>(&pl[w][0]);
  const char* klb = reinterpret_cast<const char*>(kl);
  const char* vtb = reinterpret_cast<const char*>(vt);

  #pragma unroll 1
  for (int it = 0; it < 4; ++it) {
    const int ib = w * 64 + it * 16;          // this wave's 16 query rows

    // Q B-frag: col i = lr, k(ch) = lg*8.. (direct from global, 1 KB/wave)
    bf16x8 qfrag = *reinterpret_cast<const bf16x8*>(
        &q[base + (size_t)(ib + lr) * 32 + lg * 8]);

    // ---- S^T = K · Q^T : 16 j-tiles ----
    f32x4 sacc[16];
    #pragma unroll
    for (int jt = 0; jt < 16; ++jt) sacc[jt] = (f32x4){0.f, 0.f, 0.f, 0.f};
    #pragma unroll
    for (int jt = 0; jt < 16; ++jt) {
      int byte = (jt * 16 + lr) * 64 + lg * 16;
      byte ^= ((lr & 7) << 4);
      bf16x8 kf = *reinterpret_cast<const bf16x8*>(klb + byte);
      sacc[jt] = __builtin_amdgcn_mfma_f32_16x16x32_bf16(kf, qfrag, sacc[jt], 0, 0, 0);
    }

    // ---- max-free softmax: exp in place, lane-local row sum ----
    float psum = 0.f;
    #pragma unroll
    for (int jt = 0; jt < 16; ++jt)
      #pragma unroll
      for (int r = 0; r < 4; ++r) {
        const float e = __expf(sacc[jt][r]);
        sacc[jt][r] = e;
        psum += e;
      }
    psum += __shfl_xor(psum, 16);
    psum += __shfl_xor(psum, 32);
    const float rl = 1.0f / psum;

    // ---- pack NORMALIZED P (bf16) into per-wave swizzled LDS ----
    #pragma unroll
    for (int jt = 0; jt < 16; ++jt) {
      unsigned w0 = (unsigned)f2bf(sacc[jt][0] * rl) |
                    ((unsigned)f2bf(sacc[jt][1] * rl) << 16);
      unsigned w1 = (unsigned)f2bf(sacc[jt][2] * rl) |
                    ((unsigned)f2bf(sacc[jt][3] * rl) << 16);
      int byte = lr * 512 + (jt * 16 + lg * 4) * 2;
      byte ^= ((lr & 7) << 4);
      uint2 pk; pk.x = w0; pk.y = w1;
      *reinterpret_cast<uint2*>(plb + byte) = pk;
    }
    asm volatile("s_waitcnt lgkmcnt(0)" ::: "memory");
    __builtin_amdgcn_sched_barrier(0);

    // ---- O = P · V ----
    f32x4 oacc[2];
    oacc[0] = (f32x4){0.f, 0.f, 0.f, 0.f};
    oacc[1] = (f32x4){0.f, 0.f, 0.f, 0.f};
    #pragma unroll
    for (int kt = 0; kt < 8; ++kt) {
      int pbyte = lr * 512 + (kt * 64 + lg * 16);
      pbyte ^= ((lr & 7) << 4);
      bf16x8 pf = *reinterpret_cast<const bf16x8*>(plb + pbyte);
      #pragma unroll
      for (int cht = 0; cht < 2; ++cht) {
        const int ch = cht * 16 + lr;
        int vbyte = ch * 512 + (kt * 64 + lg * 16);
        vbyte ^= ((ch & 7) << 4);
        bf16x8 vf = *reinterpret_cast<const bf16x8*>(vtb + vbyte);
        oacc[cht] = __builtin_amdgcn_mfma_f32_16x16x32_bf16(pf, vf, oacc[cht], 0, 0, 0);
      }
    }

    // ---- gate + store O in place over g: og = o * g (P already normalized) ----
    #pragma unroll
    for (int cht = 0; cht < 2; ++cht)
      #pragma unroll
      for (int r = 0; r < 4; ++r) {
        const int i = ib + lg * 4 + r;
        const size_t off = ((size_t)(n * Lc + i)) * 128 + h * 32 + cht * 16 + lr;
        const float gv = bf2f(og_ws[off]);
        og_ws[off] = f2bf(oacc[cht][r] * gv);
      }
  }
}

// ---------------------------------------------------------------------------
// K3: out^T = w2^T · (o·g)^T  -> out[c][pos] fp32, coalesced along pos.
//   og_ws already holds gated o -> B-frags are straight bf16x8 loads.
// ---------------------------------------------------------------------------
__global__ __launch_bounds__(256) void outproj_mfma(
    const unsigned short* __restrict__ og_ws,
    const unsigned short* __restrict__ w2T, const float* __restrict__ b2,
    float* __restrict__ out)
{
  const int t = threadIdx.x;
  const int w = t >> 6, l = t & 63, lr = l & 15, lg = l >> 4;
  const int pos = blockIdx.x * 64 + w * 16 + lr;

  bf16x8 zb[4];
  #pragma unroll
  for (int kt = 0; kt < 4; ++kt)
    zb[kt] = *reinterpret_cast<const bf16x8*>(
        &og_ws[(size_t)pos * 128 + kt * 32 + lg * 8]);

  #pragma unroll
  for (int ct = 0; ct < 8; ++ct) {
    f32x4 acc = (f32x4){0.f, 0.f, 0.f, 0.f};
    #pragma unroll
    for (int kt = 0; kt < 4; ++kt) {
      bf16x8 af = *reinterpret_cast<const bf16x8*>(
          &w2T[(size_t)(ct * 16 + lr) * 128 + kt * 32 + lg * 8]);
      acc = __builtin_amdgcn_mfma_f32_16x16x32_bf16(af, zb[kt], acc, 0, 0, 0);
    }
    #pragma unroll
    for (int r = 0; r < 4; ++r) {
      const int c = ct * 16 + lg * 4 + r;
      out[(size_t)c * NPOSc + pos] = acc[r] + b2[c];
    }
  }
}

// ---------------------------------------------------------------------------
extern "C" void kernel_launch(void* const* d_in, const int* in_sizes, int n_in,
                              void* d_out, int out_size, void* d_ws, size_t ws_size,
                              hipStream_t stream) {
  const float* z   = (const float*)d_in[0];
  const float* lnw = (const float*)d_in[1];
  const float* lnb = (const float*)d_in[2];
  const float* wq  = (const float*)d_in[3];
  const float* bq  = (const float*)d_in[4];
  const float* wk  = (const float*)d_in[5];
  const float* bk  = (const float*)d_in[6];
  const float* wv  = (const float*)d_in[7];
  const float* bv  = (const float*)d_in[8];
  const float* wg  = (const float*)d_in[9];
  const float* bg  = (const float*)d_in[10];
  const float* w2  = (const float*)d_in[11];
  const float* b2  = (const float*)d_in[12];
  float* out = (float*)d_out;

  const size_t S = (size_t)NPOSc * DHCc;        // 8388608 elements
  unsigned short* ws = (unsigned short*)d_ws;
  unsigned short* q_ws = ws;                    // [n][h][i][ch]
  unsigned short* k_ws = ws + S;                // [n][h][j][ch]
  unsigned short* v_ws = ws + 2 * S;            // [n][h][ch][ii] (transposed)
  unsigned short* g_ws = ws + 3 * S;            // [pos][128]; becomes o*g in attn
  unsigned short* wT   = ws + 4 * S;            // 5 x 16384 bf16 weights
  float* mus  = (float*)(ws + 5 * S);           // 65536 f32
  float* rsts = mus + NPOSc;                    // 65536 f32

  prep_stats<<<261, 256, 0, stream>>>(wq, wk, wv, wg, w2, z, wT, mus, rsts);
  ln_qkvg_mfma<<<NPOSc / 128, 256, 0, stream>>>(
      z, lnw, lnb, wT, mus, rsts, bq, bk, bv, bg, q_ws, k_ws, v_ws, g_ws);
  attn_mfma<<<dim3(Hc, Lc), 256, 0, stream>>>(q_ws, k_ws, v_ws, g_ws);
  outproj_mfma<<<NPOSc / 64, 256, 0, stream>>>(
      g_ws, wT + 4 * (DZc * DHCc), b2, out);
}

// Round 8
// 108.213 us; speedup vs baseline: 1.4629x; 1.0540x over previous
//
#include <hip/hip_runtime.h>
#include <cstdint>
#include <cstddef>

#define DZc   128
#define Lc    256
#define Hc    4
#define DCc   32
#define DHCc  128
#define NPOSc (Lc * Lc)

typedef __attribute__((ext_vector_type(8))) short bf16x8;
typedef __attribute__((ext_vector_type(4))) short bf16x4;
typedef __attribute__((ext_vector_type(4))) float f32x4;

static __device__ __forceinline__ unsigned short f2bf(float f) {
  unsigned u = __float_as_uint(f);
  u += 0x7FFFu + ((u >> 16) & 1u);     // round-to-nearest-even
  return (unsigned short)(u >> 16);
}
static __device__ __forceinline__ float bf2f(unsigned short h) {
  return __uint_as_float(((unsigned)h) << 16);
}
static __device__ __forceinline__ float sigmoidf_(float x) {
  return 1.0f / (1.0f + __expf(-x));
}

// ---------------------------------------------------------------------------
// prep: weights fp32 [k][j] -> bf16 transposed [j][k]; q-scale folded into wq.
// slot 0..3 = wq,wk,wv,wg ; slot 4 = w2 (-> w2T[c][k]).  (z stats now in K1.)
// ---------------------------------------------------------------------------
__global__ __launch_bounds__(256) void prep_weights(
    const float* __restrict__ wq, const float* __restrict__ wk,
    const float* __restrict__ wv, const float* __restrict__ wg,
    const float* __restrict__ w2, unsigned short* __restrict__ wT)
{
  const int b = blockIdx.x;  // 0..4
  const int t = threadIdx.x;
  const float* src = (b == 0) ? wq : (b == 1) ? wk : (b == 2) ? wv : (b == 3) ? wg : w2;
  unsigned short* dst = wT + (size_t)b * (DZc * DHCc);
  const float scale = (b == 0) ? 0.17677669529663687f : 1.0f;  // sqrt(1/32)
  for (int p = 0; p < 64; ++p) {
    const int idx = p * 256 + t;             // 16384 elements
    const int kk = idx >> 7, j = idx & 127;  // src[kk][j]
    dst[j * 128 + kk] = f2bf(src[idx] * scale);
  }
}

// ---------------------------------------------------------------------------
// K1 v5: LN (stats IN REGISTERS via 8-lane shfl tree) + 4 projections (MFMA).
//   128 pos/block, LDS = znl only. Phase A: lane holds 4pos x 16ch of z in
//   VGPRs, shfl_xor(1,2,4) reduce over the 8-lane channel groups, LN-apply,
//   conflict-free swizzled b128 znl writes. Phase B unchanged from R7
//   (swapped-operand q/k/g -> 8B stores; v -> transposed [ch][ii] 8B stores).
// ---------------------------------------------------------------------------
__global__ __launch_bounds__(256) void ln_qkvg_mfma(
    const float* __restrict__ z, const float* __restrict__ lnw, const float* __restrict__ lnb,
    const unsigned short* __restrict__ wT,
    const float* __restrict__ bq, const float* __restrict__ bk,
    const float* __restrict__ bv, const float* __restrict__ bg,
    unsigned short* __restrict__ q_ws, unsigned short* __restrict__ k_ws,
    unsigned short* __restrict__ v_ws, unsigned short* __restrict__ g_ws)
{
  __shared__ unsigned short znl[128 * DZc];   // 32 KB bf16 [i][c], XOR-swizzled

  const int t = threadIdx.x;
  const int pos0 = blockIdx.x * 128;
  const int n = pos0 >> 8;        // constant per block
  const int w  = t >> 6;          // wave = weight index (0=q,1=k,2=v,3=g)
  const int l  = t & 63;
  const int lr = l & 15;
  const int lg = l >> 4;

  const unsigned short* wTw = wT + (size_t)w * (DZc * DHCc);
  const float* bptr = (w == 0) ? bq : (w == 1) ? bk : (w == 2) ? bv : bg;
  const float qscale = 0.17677669529663687f;

  // v-wave bias (per jc = jt*16+lr, lr baked in)
  float biasv[8];
  #pragma unroll
  for (int jt = 0; jt < 8; ++jt) biasv[jt] = bptr[jt * 16 + lr];

  // ---- Phase A: z in regs, in-wave stats, LN, swizzled znl writes ----
  {
    const int pq = t >> 3;          // 0..31 pos-quad
    const int cg = t & 7;           // 0..7 channel group (16 ch each)
    const int gp = pos0 + pq * 4;
    const int cbase = cg * 16;

    float4 zr[16];
    #pragma unroll
    for (int cc = 0; cc < 16; ++cc)
      zr[cc] = *reinterpret_cast<const float4*>(&z[(size_t)(cbase + cc) * NPOSc + gp]);

    float s[4] = {0.f, 0.f, 0.f, 0.f}, s2[4] = {0.f, 0.f, 0.f, 0.f};
    #pragma unroll
    for (int cc = 0; cc < 16; ++cc) {
      s[0] += zr[cc].x; s2[0] += zr[cc].x * zr[cc].x;
      s[1] += zr[cc].y; s2[1] += zr[cc].y * zr[cc].y;
      s[2] += zr[cc].z; s2[2] += zr[cc].z * zr[cc].z;
      s[3] += zr[cc].w; s2[3] += zr[cc].w * zr[cc].w;
    }
    // reduce over the 8 lanes (same pq, cg 0..7): masks 1,2,4 stay in-group
    #pragma unroll
    for (int m = 1; m <= 4; m <<= 1) {
      #pragma unroll
      for (int e = 0; e < 4; ++e) {
        s[e]  += __shfl_xor(s[e],  m);
        s2[e] += __shfl_xor(s2[e], m);
      }
    }
    float mu[4], rs[4];
    #pragma unroll
    for (int e = 0; e < 4; ++e) {
      mu[e] = s[e] * (1.0f / DZc);
      const float var = s2[e] * (1.0f / DZc) - mu[e] * mu[e];
      rs[e] = rsqrtf(var + 1e-5f);
    }

    float lw[16], lb[16];
    #pragma unroll
    for (int q4 = 0; q4 < 4; ++q4) {
      const float4 a = *reinterpret_cast<const float4*>(&lnw[cbase + q4 * 4]);
      const float4 b = *reinterpret_cast<const float4*>(&lnb[cbase + q4 * 4]);
      lw[q4 * 4 + 0] = a.x; lw[q4 * 4 + 1] = a.y; lw[q4 * 4 + 2] = a.z; lw[q4 * 4 + 3] = a.w;
      lb[q4 * 4 + 0] = b.x; lb[q4 * 4 + 1] = b.y; lb[q4 * 4 + 2] = b.z; lb[q4 * 4 + 3] = b.w;
    }

    #pragma unroll
    for (int e = 0; e < 4; ++e) {
      const int i = pq * 4 + e;
      #pragma unroll
      for (int half = 0; half < 2; ++half) {
        unsigned short pk[8];
        #pragma unroll
        for (int cc = 0; cc < 8; ++cc) {
          const int c = half * 8 + cc;
          const float zc = (e == 0) ? zr[c].x : (e == 1) ? zr[c].y
                         : (e == 2) ? zr[c].z : zr[c].w;
          pk[cc] = f2bf((zc - mu[e]) * rs[e] * lw[c] + lb[c]);
        }
        int byte = i * 256 + (cbase + half * 8) * 2;
        byte ^= ((i & 7) << 4);
        *reinterpret_cast<bf16x8*>(reinterpret_cast<char*>(znl) + byte) =
            *reinterpret_cast<const bf16x8*>(pk);
      }
    }
  }
  __syncthreads();

  // ---- Phase B: GEMM in two j-half passes (bfrag live = 64 VGPRs) ----
  unsigned short* outp = (w == 0) ? q_ws : (w == 1) ? k_ws : (w == 2) ? v_ws : g_ws;
  const char* znlb = reinterpret_cast<const char*>(znl);

  #pragma unroll 1
  for (int jh = 0; jh < 2; ++jh) {
    bf16x8 bfrag[4][4];
    #pragma unroll
    for (int jt = 0; jt < 4; ++jt)
      #pragma unroll
      for (int kt = 0; kt < 4; ++kt)
        bfrag[jt][kt] = *reinterpret_cast<const bf16x8*>(
            &wTw[(size_t)(jh * 64 + jt * 16 + lr) * 128 + kt * 32 + lg * 8]);

    // bias for swapped waves: 4 consecutive jc at jc0 = jh*64+jt*16+lg*4
    float bias4[4][4];
    if (w != 2) {
      #pragma unroll
      for (int jt = 0; jt < 4; ++jt) {
        const float4 bb = *reinterpret_cast<const float4*>(
            &bptr[jh * 64 + jt * 16 + lg * 4]);
        bias4[jt][0] = bb.x; bias4[jt][1] = bb.y;
        bias4[jt][2] = bb.z; bias4[jt][3] = bb.w;
        if (w == 0) {
          #pragma unroll
          for (int r = 0; r < 4; ++r) bias4[jt][r] *= qscale;
        }
      }
    }

    #pragma unroll 1
    for (int it = 0; it < 8; ++it) {
      bf16x8 afrag[4];
      #pragma unroll
      for (int kt = 0; kt < 4; ++kt) {
        const int i = it * 16 + lr;
        int byte = i * 256 + (kt * 64 + lg * 16);
        byte ^= ((i & 7) << 4);
        afrag[kt] = *reinterpret_cast<const bf16x8*>(znlb + byte);
      }
      f32x4 acc[4];
      #pragma unroll
      for (int jt = 0; jt < 4; ++jt) acc[jt] = (f32x4){0.f, 0.f, 0.f, 0.f};

      if (w == 2) {
        // ---- v: D[pos][jc], transposed store [n][h][ch][ii] (8B) ----
        #pragma unroll
        for (int kt = 0; kt < 4; ++kt)
          #pragma unroll
          for (int jt = 0; jt < 4; ++jt)
            acc[jt] = __builtin_amdgcn_mfma_f32_16x16x32_bf16(
                afrag[kt], bfrag[jt][kt], acc[jt], 0, 0, 0);
        const int ii0 = (pos0 & 255) + it * 16 + lg * 4;
        #pragma unroll
        for (int jt = 0; jt < 4; ++jt) {
          const int jc = jh * 64 + jt * 16 + lr;
          const float bb = biasv[jh * 4 + jt];
          const int h = jc >> 5, ch = jc & 31;
          unsigned short pk[4];
          #pragma unroll
          for (int r = 0; r < 4; ++r) pk[r] = f2bf(acc[jt][r] + bb);
          *reinterpret_cast<bf16x4*>(
              &outp[((size_t)(n * 4 + h) * 32 + ch) * 256 + ii0]) =
              *reinterpret_cast<const bf16x4*>(pk);
        }
      } else {
        // ---- q/k/g: SWAPPED -> D[jc][pos], packed 8B stores along ch ----
        #pragma unroll
        for (int kt = 0; kt < 4; ++kt)
          #pragma unroll
          for (int jt = 0; jt < 4; ++jt)
            acc[jt] = __builtin_amdgcn_mfma_f32_16x16x32_bf16(
                bfrag[jt][kt], afrag[kt], acc[jt], 0, 0, 0);
        const int pos = pos0 + it * 16 + lr;
        const int ii  = pos & 255;
        #pragma unroll
        for (int jt = 0; jt < 4; ++jt) {
          const int jc0 = jh * 64 + jt * 16 + lg * 4;
          unsigned short pk[4];
          #pragma unroll
          for (int r = 0; r < 4; ++r) {
            float vv = acc[jt][r] + bias4[jt][r];
            if (w == 3) vv = sigmoidf_(vv);
            pk[r] = f2bf(vv);
          }
          unsigned short* dst;
          if (w == 3) {
            dst = &outp[(size_t)pos * 128 + jc0];
          } else {
            const int h = jc0 >> 5, ch = jc0 & 31;
            dst = &outp[((size_t)(n * 4 + h) * 256 + ii) * 32 + ch];
          }
          *reinterpret_cast<bf16x4*>(dst) = *reinterpret_cast<const bf16x4*>(pk);
        }
      }
    }
  }
}

// ---------------------------------------------------------------------------
// K2: attention per (h,n). Swapped QK^T -> lane-local row-sum; max-free
//   softmax; P bounced via HALVED per-wave LDS (4 KB, two j-half rounds ->
//   48 KB total LDS -> 3 blocks/CU). Gate values PREFETCHED at tile start.
//   O*g written in place into g_ws [pos][128].
// ---------------------------------------------------------------------------
__global__ __launch_bounds__(256) void attn_mfma(
    const unsigned short* __restrict__ q, const unsigned short* __restrict__ k,
    const unsigned short* __restrict__ v, unsigned short* og_ws)
{
  __shared__ unsigned short kl[Lc * DCc];    // 16 KB [j][ch] swizzled
  __shared__ unsigned short vt[DCc * Lc];    // 16 KB [ch][j] swizzled
  __shared__ unsigned short pl[4][16 * 128]; // 4 x 4 KB per-wave P half, swizzled

  const int t = threadIdx.x;
  const int h = blockIdx.x, n = blockIdx.y;
  const int w = t >> 6, l = t & 63, lr = l & 15, lg = l >> 4;
  const size_t base = ((size_t)(n * Hc + h)) * (Lc * DCc);

  // ---- stage K: [j][ch] bf16, swizzle byte ^= (j&7)<<4 ----
  #pragma unroll
  for (int pass = 0; pass < 4; ++pass) {
    const int cid = pass * 256 + t;           // 1024 x 16B chunks
    const int j = cid >> 2, c = cid & 3;
    bf16x8 kk = *reinterpret_cast<const bf16x8*>(&k[base + (size_t)j * 32 + c * 8]);
    int byte = j * 64 + c * 16;
    byte ^= ((j & 7) << 4);
    *reinterpret_cast<bf16x8*>(reinterpret_cast<char*>(kl) + byte) = kk;
  }
  // ---- stage V (pre-transposed): straight copy, swizzle byte ^= (ch&7)<<4 ----
  #pragma unroll
  for (int pass = 0; pass < 4; ++pass) {
    const int cid = pass * 256 + t;           // 1024 x 16B chunks
    const int ch = cid >> 5, c = cid & 31;
    bf16x8 vv = *reinterpret_cast<const bf16x8*>(&v[base + (size_t)ch * 256 + c * 8]);
    int byte = ch * 512 + c * 16;
    byte ^= ((ch & 7) << 4);
    *reinterpret_cast<bf16x8*>(reinterpret_cast<char*>(vt) + byte) = vv;
  }
  __syncthreads();

  char* plb = reinterpret_cast<char*>(&pl[w][0]);
  const char* klb = reinterpret_cast<const char*>(kl);
  const char* vtb = reinterpret_cast<const char*>(vt);

  #pragma unroll 1
  for (int it = 0; it < 4; ++it) {
    const int ib = w * 64 + it * 16;          // this wave's 16 query rows

    // ---- prefetch gate values (latency hides under QK^T + softmax) ----
    unsigned short gpre[8];
    #pragma unroll
    for (int cht = 0; cht < 2; ++cht)
      #pragma unroll
      for (int r = 0; r < 4; ++r) {
        const int i = ib + lg * 4 + r;
        gpre[cht * 4 + r] =
            og_ws[((size_t)(n * Lc + i)) * 128 + h * 32 + cht * 16 + lr];
      }

    // Q B-frag: col i = lr, k(ch) = lg*8.. (direct from global, 1 KB/wave)
    bf16x8 qfrag = *reinterpret_cast<const bf16x8*>(
        &q[base + (size_t)(ib + lr) * 32 + lg * 8]);

    // ---- S^T = K · Q^T : 16 j-tiles ----
    f32x4 sacc[16];
    #pragma unroll
    for (int jt = 0; jt < 16; ++jt) sacc[jt] = (f32x4){0.f, 0.f, 0.f, 0.f};
    #pragma unroll
    for (int jt = 0; jt < 16; ++jt) {
      int byte = (jt * 16 + lr) * 64 + lg * 16;
      byte ^= ((lr & 7) << 4);
      bf16x8 kf = *reinterpret_cast<const bf16x8*>(klb + byte);
      sacc[jt] = __builtin_amdgcn_mfma_f32_16x16x32_bf16(kf, qfrag, sacc[jt], 0, 0, 0);
    }

    // ---- max-free softmax: exp in place, lane-local row sum ----
    float psum = 0.f;
    #pragma unroll
    for (int jt = 0; jt < 16; ++jt)
      #pragma unroll
      for (int r = 0; r < 4; ++r) {
        const float e = __expf(sacc[jt][r]);
        sacc[jt][r] = e;
        psum += e;
      }
    psum += __shfl_xor(psum, 16);
    psum += __shfl_xor(psum, 32);
    const float rl = 1.0f / psum;

    // ---- PV in two j-half rounds through the 4 KB per-wave buffer ----
    f32x4 oacc[2];
    oacc[0] = (f32x4){0.f, 0.f, 0.f, 0.f};
    oacc[1] = (f32x4){0.f, 0.f, 0.f, 0.f};
    #pragma unroll
    for (int jh2 = 0; jh2 < 2; ++jh2) {
      // pack normalized P (bf16) for jt = jh2*8 .. +8
      #pragma unroll
      for (int jt8 = 0; jt8 < 8; ++jt8) {
        const int jt = jh2 * 8 + jt8;
        unsigned w0 = (unsigned)f2bf(sacc[jt][0] * rl) |
                      ((unsigned)f2bf(sacc[jt][1] * rl) << 16);
        unsigned w1 = (unsigned)f2bf(sacc[jt][2] * rl) |
                      ((unsigned)f2bf(sacc[jt][3] * rl) << 16);
        int byte = lr * 256 + (jt8 * 16 + lg * 4) * 2;
        byte ^= ((lr & 7) << 4);
        uint2 pk; pk.x = w0; pk.y = w1;
        *reinterpret_cast<uint2*>(plb + byte) = pk;
      }
      asm volatile("s_waitcnt lgkmcnt(0)" ::: "memory");
      __builtin_amdgcn_sched_barrier(0);

      #pragma unroll
      for (int kt4 = 0; kt4 < 4; ++kt4) {
        int pbyte = lr * 256 + (kt4 * 64 + lg * 16);
        pbyte ^= ((lr & 7) << 4);
        bf16x8 pf = *reinterpret_cast<const bf16x8*>(plb + pbyte);
        const int kt = jh2 * 4 + kt4;
        #pragma unroll
        for (int cht = 0; cht < 2; ++cht) {
          const int ch = cht * 16 + lr;
          int vbyte = ch * 512 + (kt * 64 + lg * 16);
          vbyte ^= ((ch & 7) << 4);
          bf16x8 vf = *reinterpret_cast<const bf16x8*>(vtb + vbyte);
          oacc[cht] = __builtin_amdgcn_mfma_f32_16x16x32_bf16(pf, vf, oacc[cht], 0, 0, 0);
        }
      }
    }

    // ---- gate + store O in place over g (P already normalized) ----
    #pragma unroll
    for (int cht = 0; cht < 2; ++cht)
      #pragma unroll
      for (int r = 0; r < 4; ++r) {
        const int i = ib + lg * 4 + r;
        const size_t off = ((size_t)(n * Lc + i)) * 128 + h * 32 + cht * 16 + lr;
        og_ws[off] = f2bf(oacc[cht][r] * bf2f(gpre[cht * 4 + r]));
      }
  }
}

// ---------------------------------------------------------------------------
// K3: out^T = w2^T · (o·g)^T  -> out[c][pos] fp32, coalesced along pos.
// ---------------------------------------------------------------------------
__global__ __launch_bounds__(256) void outproj_mfma(
    const unsigned short* __restrict__ og_ws,
    const unsigned short* __restrict__ w2T, const float* __restrict__ b2,
    float* __restrict__ out)
{
  const int t = threadIdx.x;
  const int w = t >> 6, l = t & 63, lr = l & 15, lg = l >> 4;
  const int pos = blockIdx.x * 64 + w * 16 + lr;

  bf16x8 zb[4];
  #pragma unroll
  for (int kt = 0; kt < 4; ++kt)
    zb[kt] = *reinterpret_cast<const bf16x8*>(
        &og_ws[(size_t)pos * 128 + kt * 32 + lg * 8]);

  #pragma unroll
  for (int ct = 0; ct < 8; ++ct) {
    f32x4 acc = (f32x4){0.f, 0.f, 0.f, 0.f};
    #pragma unroll
    for (int kt = 0; kt < 4; ++kt) {
      bf16x8 af = *reinterpret_cast<const bf16x8*>(
          &w2T[(size_t)(ct * 16 + lr) * 128 + kt * 32 + lg * 8]);
      acc = __builtin_amdgcn_mfma_f32_16x16x32_bf16(af, zb[kt], acc, 0, 0, 0);
    }
    #pragma unroll
    for (int r = 0; r < 4; ++r) {
      const int c = ct * 16 + lg * 4 + r;
      out[(size_t)c * NPOSc + pos] = acc[r] + b2[c];
    }
  }
}

// ---------------------------------------------------------------------------
extern "C" void kernel_launch(void* const* d_in, const int* in_sizes, int n_in,
                              void* d_out, int out_size, void* d_ws, size_t ws_size,
                              hipStream_t stream) {
  const float* z   = (const float*)d_in[0];
  const float* lnw = (const float*)d_in[1];
  const float* lnb = (const float*)d_in[2];
  const float* wq  = (const float*)d_in[3];
  const float* bq  = (const float*)d_in[4];
  const float* wk  = (const float*)d_in[5];
  const float* bk  = (const float*)d_in[6];
  const float* wv  = (const float*)d_in[7];
  const float* bv  = (const float*)d_in[8];
  const float* wg  = (const float*)d_in[9];
  const float* bg  = (const float*)d_in[10];
  const float* w2  = (const float*)d_in[11];
  const float* b2  = (const float*)d_in[12];
  float* out = (float*)d_out;

  const size_t S = (size_t)NPOSc * DHCc;        // 8388608 elements
  unsigned short* ws = (unsigned short*)d_ws;
  unsigned short* q_ws = ws;                    // [n][h][i][ch]
  unsigned short* k_ws = ws + S;                // [n][h][j][ch]
  unsigned short* v_ws = ws + 2 * S;            // [n][h][ch][ii] (transposed)
  unsigned short* g_ws = ws + 3 * S;            // [pos][128]; becomes o*g in attn
  unsigned short* wT   = ws + 4 * S;            // 5 x 16384 bf16 weights

  prep_weights<<<5, 256, 0, stream>>>(wq, wk, wv, wg, w2, wT);
  ln_qkvg_mfma<<<NPOSc / 128, 256, 0, stream>>>(
      z, lnw, lnb, wT, bq, bk, bv, bg, q_ws, k_ws, v_ws, g_ws);
  attn_mfma<<<dim3(Hc, Lc), 256, 0, stream>>>(q_ws, k_ws, v_ws, g_ws);
  outproj_mfma<<<NPOSc / 64, 256, 0, stream>>>(
      g_ws, wT + 4 * (DZc * DHCc), b2, out);
}